// Round 10
// baseline (273.803 us; speedup 1.0000x reference)
//
#include <hip/hip_runtime.h>
#include <hip/hip_bf16.h>
#include <math.h>

#define B_ 4
#define N_ 2048
#define D_ 1024
#define H_ 16
#define HD_ 64
#define SCALE_ 0.015625f   // 1/HD
#define MD_ ((size_t)B_ * N_ * D_)   // 8388608
#define DD_ ((size_t)D_ * D_)        // 1048576
#define BHSZ_ ((size_t)N_ * HD_)     // 131072 elems per (b,h) frag slab
// folded into q at RoPE: SCALE * log2(e)
#define QSC_ 0.0225421143f

typedef __hip_bfloat16 bf16;
typedef __attribute__((ext_vector_type(8))) __bf16 bf16x8;
typedef __attribute__((ext_vector_type(4))) float f32x4;
typedef __attribute__((ext_vector_type(16))) float f32x16;

__device__ __forceinline__ float b2f(bf16 x) { return __bfloat162float(x); }
__device__ __forceinline__ bf16 f2b(float x) { return __float2bfloat16(x); }

// exact (RNE) pack of two floats to bf16 pair (elem0 low)
__device__ __forceinline__ unsigned int pk2(float a, float b) {
  union { bf16 h[2]; unsigned int u; } t;
  t.h[0] = f2b(a); t.h[1] = f2b(b);
  return t.u;
}
// truncating pack (cheap; for P fragments only, e >= 0)
__device__ __forceinline__ unsigned int pk2t(float a, float b) {
  return (__float_as_uint(a) >> 16) | (__float_as_uint(b) & 0xffff0000u);
}

// half-wave swap (T12 primitive; verified round 7):
// post: a = [a.lo | b.lo-from-lane^32], b = [a.hi-from-lane^32 | b.hi]
__device__ __forceinline__ void plswap(unsigned int& a, unsigned int& b) {
  auto r = __builtin_amdgcn_permlane32_swap(a, b, false, false);
  a = r[0]; b = r[1];
}

// async global->LDS, 16 bytes per lane
__device__ __forceinline__ void gl_lds16(const bf16* g, bf16* l) {
  __builtin_amdgcn_global_load_lds(
      (const __attribute__((address_space(1))) void*)g,
      (__attribute__((address_space(3))) void*)l, 16, 0, 0);
}

// ---------------------------------------------------------------------------
// Fused fp32 -> bf16 conversion of x, Wq, Wk, Wv, Wo (one launch).
// ---------------------------------------------------------------------------
__global__ __launch_bounds__(256) void cvt_all(
    const float* __restrict__ x,  const float* __restrict__ wq,
    const float* __restrict__ wk, const float* __restrict__ wv,
    const float* __restrict__ wo, bf16* __restrict__ xb,
    bf16* __restrict__ wb)
{
  const int blk = blockIdx.x;
  const float* s; bf16* d; int i;
  if (blk < 4096)      { s = x;  d = xb;           i = blk; }
  else if (blk < 4608) { s = wq; d = wb;           i = blk - 4096; }
  else if (blk < 5120) { s = wk; d = wb + DD_;     i = blk - 4608; }
  else if (blk < 5632) { s = wv; d = wb + 2 * DD_; i = blk - 5120; }
  else                 { s = wo; d = wb + 3 * DD_; i = blk - 5632; }
  int e = (i * 256 + threadIdx.x) * 8;
  float4 a = *reinterpret_cast<const float4*>(s + e);
  float4 b = *reinterpret_cast<const float4*>(s + e + 4);
  bf16 t[8] = {f2b(a.x), f2b(a.y), f2b(a.z), f2b(a.w),
               f2b(b.x), f2b(b.y), f2b(b.z), f2b(b.w)};
  *reinterpret_cast<int4*>(d + e) = *reinterpret_cast<const int4*>(t);
}

// ---------------------------------------------------------------------------
// MFMA GEMM — verified structure, BK=64 (round-8 WIN: halved barrier drains).
// C[M,N] = A[M,K] @ W[N,K]^T, bf16 in, fp32 accumulate. 128x128 tile,
// 4 waves 2x2, per barrier-pair: 16 ds_read_b128 + 32 MFMA (2 k-substeps).
// 16x32 chunk XOR slot swizzle (bank-conflict-free, proven). LDS 32 KB.
// Tile chunk map: c = rg*2 + kh  (rg = row-group 0..7, kh = k-half 0..1).
// MODE 0: fused QKV epilogue — q,k frag-tiled F[bh][t32][s][hi][m][8],
//         v as Vf[bh][t32][hf][hi][hd][8].
// MODE 1: fp32 output + bias.
// ---------------------------------------------------------------------------
template <int MODE>
__global__ __launch_bounds__(256) void mgemm(
    const bf16* __restrict__ A, const bf16* __restrict__ W,
    const float* __restrict__ bias, void* __restrict__ Cv,
    int M, int N, int K)
{
  __shared__ bf16 As[128 * 64];   // 16 KB: 16 chunks [rg][kh][16][32]
  __shared__ bf16 Ws[128 * 64];   // 16 KB

  const int tid  = threadIdx.x;
  const int w    = tid >> 6;
  const int lane = tid & 63;
  const int bm   = blockIdx.y * 128;
  const int bn   = blockIdx.x * 128;

  const int wr = (w >> 1) * 64;
  const int wc = (w & 1) * 64;
  const int lm   = lane & 15;
  const int quad = lane >> 4;

  // staging: r = lane>>2 within chunk, swizzled global slot
  const int srow = lane >> 2;                        // 0..15
  const int sslot = (lane & 3) ^ ((lane >> 3) & 3);  // global slot fetched
  const int scol = sslot * 8;

  // reader swizzle: logical slot quad of row lm -> phys slot
  const int rsw  = (quad ^ ((lm >> 1) & 3)) * 8;

  // chunk row-group base for this wave's frag reads
  const int crgA = wr >> 4;   // A chunks rg = crgA + mi
  const int crgB = wc >> 4;   // W chunks rg = crgB + ni

  f32x4 acc[4][4] = {};

  for (int k0 = 0; k0 < K; k0 += 64) {
#pragma unroll
    for (int cc = 0; cc < 4; ++cc) {
      int c  = w * 4 + cc;        // 0..15
      int rg = c >> 1;
      int kh = c & 1;
      int r  = rg * 16 + srow;
      size_t gk = (size_t)k0 + kh * 32 + scol;
      gl_lds16(A + (size_t)(bm + r) * K + gk, &As[c * 512]);
      gl_lds16(W + (size_t)(bn + r) * K + gk, &Ws[c * 512]);
    }
    __syncthreads();

#pragma unroll
    for (int ks = 0; ks < 2; ++ks) {
      bf16x8 af[4], bf_[4];
#pragma unroll
      for (int mi = 0; mi < 4; ++mi)
        af[mi] = *reinterpret_cast<const bf16x8*>(
            &As[((crgA + mi) * 2 + ks) * 512 + lm * 32 + rsw]);
#pragma unroll
      for (int ni = 0; ni < 4; ++ni)
        bf_[ni] = *reinterpret_cast<const bf16x8*>(
            &Ws[((crgB + ni) * 2 + ks) * 512 + lm * 32 + rsw]);

#pragma unroll
      for (int mi = 0; mi < 4; ++mi)
#pragma unroll
        for (int ni = 0; ni < 4; ++ni)
          acc[mi][ni] = __builtin_amdgcn_mfma_f32_16x16x32_bf16(
              af[mi], bf_[ni], acc[mi][ni], 0, 0, 0);
    }
    __syncthreads();
  }

#pragma unroll
  for (int mi = 0; mi < 4; ++mi) {
#pragma unroll
    for (int r = 0; r < 4; ++r) {
      int row = bm + wr + mi * 16 + quad * 4 + r;
#pragma unroll
      for (int ni = 0; ni < 4; ++ni) {
        int col = bn + wc + ni * 16 + lm;
        float v = acc[mi][ni][r];
        if (MODE == 1) {
          v += bias[col];
          reinterpret_cast<float*>(Cv)[(size_t)row * N + col] = v;
        } else {
          int reg = col >> 10;            // 0=q, 1=k, 2=v
          int cc  = col & 1023;
          int bb  = row >> 11;            // N_ == 2048
          int n   = row & (N_ - 1);
          int hh  = cc >> 6;
          int dd  = cc & 63;
          if (reg < 2) {
            // frag-tiled F[bh][t32][s][hi][m][8]: d = 16s+8hi+j, m = n&31
            int t32 = n >> 5, m = n & 31;
            int s = dd >> 4, hb = (dd >> 3) & 1, j = dd & 7;
            reinterpret_cast<bf16*>(Cv)[(size_t)reg * MD_ +
                (size_t)(bb * H_ + hh) * BHSZ_ +
                (size_t)t32 * 2048 + s * 512 + hb * 256 + m * 8 + j] = f2b(v);
          } else {
            // Vf[bh][t32][hf][hi][hd][8]; key = 32*t32 + 16*hf + 8*hi + j
            int t32 = n >> 5, kk = n & 31;
            int hf = kk >> 4, hb = (kk >> 3) & 1, j = kk & 7;
            reinterpret_cast<bf16*>(Cv)[2 * MD_ +
                (size_t)(bb * H_ + hh) * BHSZ_ +
                (size_t)t32 * 2048 + hf * 1024 + hb * 512 + dd * 8 + j] = f2b(v);
          }
        }
      }
    }
  }
}

// ---------------------------------------------------------------------------
// In-place RoPE on frag-tiled Q and K (round-0 VERIFIED). Each thread owns
// one 16B block = (bh, t32, s, hi, m, j=0..7) -> 4 interleaved pairs, all
// with n = 32*t32 + m, i = 8s + 4hi + p. Fully coalesced 16B r/w.
// Q half additionally folds QSC_ (= SCALE * log2e).
// ---------------------------------------------------------------------------
__global__ __launch_bounds__(256) void rope_inplace(bf16* __restrict__ qf,
                                                    bf16* __restrict__ kf)
{
  const int half = blockIdx.x >> 12;        // 0 = q, 1 = k
  const int blk  = blockIdx.x & 4095;
  bf16* base = half ? kf : qf;
  const float LN_THETA = 9.210340371976184f;

  size_t e = ((size_t)blk * 256 + threadIdx.x) * 8;
  int within = (int)(e & (BHSZ_ - 1));
  int t32 = within >> 11;
  int rem = within & 2047;
  int s  = rem >> 9;
  int hb = (rem >> 8) & 1;
  int m  = (rem >> 3) & 31;
  int n  = t32 * 32 + m;

  uint4 raw = *reinterpret_cast<const uint4*>(base + e);
  unsigned int pr[4] = {raw.x, raw.y, raw.z, raw.w};
  unsigned int outw[4];
#pragma unroll
  for (int p = 0; p < 4; ++p) {
    int i = s * 8 + hb * 4 + p;
    float inv = __expf(-((float)(2 * i) / (float)HD_) * LN_THETA);
    float ang = (float)n * inv;
    float sv, cv;
    sincosf(ang, &sv, &cv);
    float a = b2f(((bf16*)&pr[p])[0]);
    float c = b2f(((bf16*)&pr[p])[1]);
    float r0 = a * cv - c * sv;
    float r1 = c * cv + a * sv;
    if (half == 0) { r0 *= QSC_; r1 *= QSC_; }
    outw[p] = pk2(r0, r1);
  }
  uint4 o = {outw[0], outw[1], outw[2], outw[3]};
  *reinterpret_cast<uint4*>(base + e) = o;
}

// ---------------------------------------------------------------------------
// Flash attention v4 + T14 issue-early:
// transpose formulation (S^T = K Q^T, O^T = V^T P^T, mfma_f32_32x32x16_bf16),
// shift-free softmax, 2-way key-split + LDS combine, frag-tiled operands,
// T12 permlane P-swap (round 7).
// T14: (1) K-fragments for tile kst+2 prefetched into registers at the TOP
// of iteration kst (manual software pipeline across the backedge — compiler
// won't do this for a dynamic-trip loop), hiding K-load latency under the
// current tile's QK+softmax+PV; (2) all 4 V-fragments hoisted to the top of
// the iteration, ~150 cy before first PV use. +32 VGPR, guards wave-uniform.
// C/D: col=lane&31, row=(reg&3)+8*(reg>>2)+4*(lane>>5)  [m74/m101].
// ---------------------------------------------------------------------------
__global__ __launch_bounds__(128) void fattn4_kernel(
    const bf16* __restrict__ Qf, const bf16* __restrict__ Kf,
    const bf16* __restrict__ Vf, bf16* __restrict__ O)
{
  __shared__ float Ls[32 * 64];
  __shared__ float Ll[64];

  const int wv   = threadIdx.x >> 6;       // key-split half 0/1
  const int lane = threadIdx.x & 63;
  const int blk  = blockIdx.x;             // 0..4095
  const int xcd  = blk & 7;
  const int j    = blk >> 3;               // 0..511
  const int qt   = 63 - (j >> 3);          // big q-tiles dispatched first
  const int bh   = xcd * 8 + (j & 7);      // 8 bh per XCD group
  const int b    = bh >> 4;
  const int h    = bh & 15;
  const int col  = lane & 31;              // q-row / hd-row within frag
  const int hi   = lane >> 5;              // lane half

  const bf16* Qb = Qf + (size_t)bh * BHSZ_ + (size_t)qt * 2048 + hi * 256 + col * 8;
  const bf16* Kb = Kf + (size_t)bh * BHSZ_ + hi * 256 + col * 8;
  const bf16* Vb = Vf + (size_t)bh * BHSZ_ + hi * 512 + col * 8;

  bf16x8 qb[4];
#pragma unroll
  for (int s = 0; s < 4; ++s)
    qb[s] = *reinterpret_cast<const bf16x8*>(Qb + s * 512);

  f32x16 o0 = {}, o1 = {};
  float lsum = 0.f;

  // prologue K-prefetch (tile index wv always exists: 64 tiles per bh)
  bf16x8 kn[4];
  {
    const bf16* kp0 = Kb + (size_t)wv * 2048;
#pragma unroll
    for (int s = 0; s < 4; ++s)
      kn[s] = *reinterpret_cast<const bf16x8*>(kp0 + s * 512);
  }

  for (int kst = wv; kst <= qt; kst += 2) {
    // current K from prefetch registers
    bf16x8 ka[4];
#pragma unroll
    for (int s = 0; s < 4; ++s) ka[s] = kn[s];

    // issue next-tile K prefetch (hides under this tile's QK+softmax+PV)
    if (kst + 2 <= qt) {
      const bf16* kp2 = Kb + (size_t)(kst + 2) * 2048;
#pragma unroll
      for (int s = 0; s < 4; ++s)
        kn[s] = *reinterpret_cast<const bf16x8*>(kp2 + s * 512);
    }

    // issue current V loads early (hides under QK+softmax)
    const bf16* vp = Vb + (size_t)kst * 2048;
    bf16x8 v00 = *reinterpret_cast<const bf16x8*>(vp);
    bf16x8 v01 = *reinterpret_cast<const bf16x8*>(vp + 256);
    bf16x8 v10 = *reinterpret_cast<const bf16x8*>(vp + 1024);
    bf16x8 v11 = *reinterpret_cast<const bf16x8*>(vp + 1024 + 256);

    f32x16 st = {};
#pragma unroll
    for (int s = 0; s < 4; ++s)
      st = __builtin_amdgcn_mfma_f32_32x32x16_bf16(ka[s], qb[s], st, 0, 0, 0);

    float pe[16];
    if (kst == qt) {
#pragma unroll
      for (int r = 0; r < 16; ++r) {
        int koff = (r & 3) + 8 * (r >> 2) + 4 * hi;
        float e = (koff <= col) ? exp2f(st[r]) : 0.f;
        pe[r] = e; lsum += e;
      }
    } else {
#pragma unroll
      for (int r = 0; r < 16; ++r) {
        float e = exp2f(st[r]);
        pe[r] = e; lsum += e;
      }
    }

#pragma unroll
    for (int hf = 0; hf < 2; ++hf) {
      unsigned int a0 = pk2t(pe[8 * hf + 0], pe[8 * hf + 1]);
      unsigned int a1 = pk2t(pe[8 * hf + 2], pe[8 * hf + 3]);
      unsigned int b0 = pk2t(pe[8 * hf + 4], pe[8 * hf + 5]);
      unsigned int b1 = pk2t(pe[8 * hf + 6], pe[8 * hf + 7]);
      plswap(a0, b0);            // a0 -> pb.x, b0 -> pb.z
      plswap(a1, b1);            // a1 -> pb.y, b1 -> pb.w
      union { uint4 u; bf16x8 v; } pb;
      pb.u.x = a0;
      pb.u.y = a1;
      pb.u.z = b0;
      pb.u.w = b1;

      bf16x8 va = hf ? v10 : v00;
      bf16x8 vb = hf ? v11 : v01;
      o0 = __builtin_amdgcn_mfma_f32_32x32x16_bf16(va, pb.v, o0, 0, 0, 0);
      o1 = __builtin_amdgcn_mfma_f32_32x32x16_bf16(vb, pb.v, o1, 0, 0, 0);
    }
  }

  if (wv == 1) {
#pragma unroll
    for (int r = 0; r < 16; ++r) {
      Ls[r * 64 + lane]        = o0[r];
      Ls[(16 + r) * 64 + lane] = o1[r];
    }
    Ll[lane] = lsum;
  }
  __syncthreads();
  if (wv == 0) {
    float lt = lsum + Ll[lane];
    lt += __shfl_xor(lt, 32);
    float inv = 1.f / lt;
#pragma unroll
    for (int r = 0; r < 16; ++r) {
      o0[r] = (o0[r] + Ls[r * 64 + lane]) * inv;
      o1[r] = (o1[r] + Ls[(16 + r) * 64 + lane]) * inv;
    }
    bf16* Op = O + ((size_t)(b * N_ + 32 * qt + col)) * D_ + h * HD_;
#pragma unroll
    for (int g = 0; g < 4; ++g) {
      uint2 u;
      u.x = pk2(o0[4 * g + 0], o0[4 * g + 1]);
      u.y = pk2(o0[4 * g + 2], o0[4 * g + 3]);
      *reinterpret_cast<uint2*>(Op + 8 * g + 4 * hi) = u;
      u.x = pk2(o1[4 * g + 0], o1[4 * g + 1]);
      u.y = pk2(o1[4 * g + 2], o1[4 * g + 3]);
      *reinterpret_cast<uint2*>(Op + 32 + 8 * g + 4 * hi) = u;
    }
  }
}

// ---------------------------------------------------------------------------
extern "C" void kernel_launch(void* const* d_in, const int* in_sizes, int n_in,
                              void* d_out, int out_size, void* d_ws, size_t ws_size,
                              hipStream_t stream)
{
  const float* x  = (const float*)d_in[0];
  const float* Wq = (const float*)d_in[1];
  const float* Wk = (const float*)d_in[2];
  const float* Wv = (const float*)d_in[3];
  const float* Wo = (const float*)d_in[4];
  const float* bo = (const float*)d_in[5];
  float* out = (float*)d_out;

  const int M = B_ * N_;                    // 8192

  bf16* xb  = (bf16*)d_ws;                  // x bf16; dead after QKV -> ao
  bf16* qf  = xb + MD_;                     // Qf | Kf | Vf contiguous slabs
  bf16* kf  = qf + MD_;
  bf16* vf  = kf + MD_;
  bf16* Wqb = vf + MD_;                     // Wq|Wk|Wv|Wo bf16
  bf16* Wob = Wqb + 3 * DD_;
  bf16* ao  = xb;

  cvt_all<<<6144, 256, 0, stream>>>(x, Wq, Wk, Wv, Wo, xb, Wqb);

  // fused QKV: C[8192, 3072] vs [Wq;Wk;Wv]; writes Qf,Kf,Vf frag-tiled
  mgemm<0><<<dim3(24, 64), 256, 0, stream>>>(xb, Wqb, nullptr, qf, M, 3 * D_, D_);

  // in-place RoPE on Qf (with QSC fold) and Kf: 2 * 4096 blocks
  rope_inplace<<<8192, 256, 0, stream>>>(qf, kf);

  // one block (2 key-split waves) per (bh, 32-row q-tile): 4096 blocks
  fattn4_kernel<<<4096, 128, 0, stream>>>(qf, kf, vf, ao);

  mgemm<1><<<dim3(8, 64), 256, 0, stream>>>(ao, Wob, bo, out, M, D_, D_);
}

// Round 11
// 265.756 us; speedup vs baseline: 1.0303x; 1.0303x over previous
//
#include <hip/hip_runtime.h>
#include <hip/hip_bf16.h>
#include <math.h>

#define B_ 4
#define N_ 2048
#define D_ 1024
#define H_ 16
#define HD_ 64
#define SCALE_ 0.015625f   // 1/HD
#define MD_ ((size_t)B_ * N_ * D_)   // 8388608
#define DD_ ((size_t)D_ * D_)        // 1048576
#define BHSZ_ ((size_t)N_ * HD_)     // 131072 elems per (b,h) frag slab
// folded into q at RoPE: SCALE * log2(e)
#define QSC_ 0.0225421143f

typedef __hip_bfloat16 bf16;
typedef __attribute__((ext_vector_type(8))) __bf16 bf16x8;
typedef __attribute__((ext_vector_type(4))) float f32x4;
typedef __attribute__((ext_vector_type(16))) float f32x16;

__device__ __forceinline__ float b2f(bf16 x) { return __bfloat162float(x); }
__device__ __forceinline__ bf16 f2b(float x) { return __float2bfloat16(x); }

// exact (RNE) pack of two floats to bf16 pair (elem0 low)
__device__ __forceinline__ unsigned int pk2(float a, float b) {
  union { bf16 h[2]; unsigned int u; } t;
  t.h[0] = f2b(a); t.h[1] = f2b(b);
  return t.u;
}
// truncating pack (cheap; for P fragments only, e >= 0)
__device__ __forceinline__ unsigned int pk2t(float a, float b) {
  return (__float_as_uint(a) >> 16) | (__float_as_uint(b) & 0xffff0000u);
}

// half-wave swap (T12 primitive; verified round 7):
// post: a = [a.lo | b.lo-from-lane^32], b = [a.hi-from-lane^32 | b.hi]
__device__ __forceinline__ void plswap(unsigned int& a, unsigned int& b) {
  auto r = __builtin_amdgcn_permlane32_swap(a, b, false, false);
  a = r[0]; b = r[1];
}

// async global->LDS, 16 bytes per lane
__device__ __forceinline__ void gl_lds16(const bf16* g, bf16* l) {
  __builtin_amdgcn_global_load_lds(
      (const __attribute__((address_space(1))) void*)g,
      (__attribute__((address_space(3))) void*)l, 16, 0, 0);
}

// ---------------------------------------------------------------------------
// Fused fp32 -> bf16 conversion of x, Wq, Wk, Wv, Wo (one launch).
// ---------------------------------------------------------------------------
__global__ __launch_bounds__(256) void cvt_all(
    const float* __restrict__ x,  const float* __restrict__ wq,
    const float* __restrict__ wk, const float* __restrict__ wv,
    const float* __restrict__ wo, bf16* __restrict__ xb,
    bf16* __restrict__ wb)
{
  const int blk = blockIdx.x;
  const float* s; bf16* d; int i;
  if (blk < 4096)      { s = x;  d = xb;           i = blk; }
  else if (blk < 4608) { s = wq; d = wb;           i = blk - 4096; }
  else if (blk < 5120) { s = wk; d = wb + DD_;     i = blk - 4608; }
  else if (blk < 5632) { s = wv; d = wb + 2 * DD_; i = blk - 5120; }
  else                 { s = wo; d = wb + 3 * DD_; i = blk - 5632; }
  int e = (i * 256 + threadIdx.x) * 8;
  float4 a = *reinterpret_cast<const float4*>(s + e);
  float4 b = *reinterpret_cast<const float4*>(s + e + 4);
  bf16 t[8] = {f2b(a.x), f2b(a.y), f2b(a.z), f2b(a.w),
               f2b(b.x), f2b(b.y), f2b(b.z), f2b(b.w)};
  *reinterpret_cast<int4*>(d + e) = *reinterpret_cast<const int4*>(t);
}

// ---------------------------------------------------------------------------
// MFMA GEMM — BK=64 (round-8 WIN), MFMA shape switched 16x16x32 ->
// 32x32x16 (this round): half the MFMA instructions at the faster 32x32
// pipe rate (2382-2495 vs 2075-2176 TF ubench) for an issue-bound kernel.
// C[M,N] = A[M,K] @ W[N,K]^T, bf16 in, fp32 accumulate. 128x128 tile,
// 4 waves 2x2, wave output 64x64 = 2x2 frags of 32x32; 4 k-substeps of 16.
// Per K-step/wave: 16 ds_read_b128 + 16 MFMA.
// A/B lane layout (HW-verified in fattn4): row = lane&31, k = (lane>>5)*8+j.
// C/D (m74/m101): col = lane&31, row = (reg&3)+8*(reg>>2)+4*(lane>>5).
// LDS staging/layout UNCHANGED: 16x32-col chunks c = rg*2+kh, XOR slot
// swizzle (row r, global slot g at phys g^((r>>1)&3)); reader derives
// rg = row>>4, rr = row&15, g = ks*2+(lane>>5), phys = (g&3)^((rr>>1)&3).
// MODE 0: fused QKV epilogue — q,k frag-tiled F[bh][t32][s][hi][m][8],
//         v as Vf[bh][t32][hf][hi][hd][8]  (scatter body unchanged).
// MODE 1: fp32 output + bias.
// ---------------------------------------------------------------------------
template <int MODE>
__global__ __launch_bounds__(256) void mgemm(
    const bf16* __restrict__ A, const bf16* __restrict__ W,
    const float* __restrict__ bias, void* __restrict__ Cv,
    int M, int N, int K)
{
  __shared__ bf16 As[128 * 64];   // 16 KB: 16 chunks [rg][kh][16][32]
  __shared__ bf16 Ws[128 * 64];   // 16 KB

  const int tid  = threadIdx.x;
  const int w    = tid >> 6;
  const int lane = tid & 63;
  const int bm   = blockIdx.y * 128;
  const int bn   = blockIdx.x * 128;

  const int wr  = (w >> 1) * 64;
  const int wc  = (w & 1) * 64;
  const int l31 = lane & 31;
  const int h2  = lane >> 5;

  // staging: r = lane>>2 within chunk, swizzled global slot (unchanged)
  const int srow = lane >> 2;                        // 0..15
  const int sslot = (lane & 3) ^ ((lane >> 3) & 3);  // global slot fetched
  const int scol = sslot * 8;

  // per-fi/fj row-derived read constants
  // r_local = base + l31; rr = r_local & 15; rg = r_local >> 4
  const int rlA0 = wr + l31,      rlA1 = wr + 32 + l31;
  const int rlB0 = wc + l31,      rlB1 = wc + 32 + l31;
  const int rrA0 = rlA0 & 15,     rgA0 = rlA0 >> 4;
  const int rrA1 = rlA1 & 15,     rgA1 = rlA1 >> 4;
  const int rrB0 = rlB0 & 15,     rgB0 = rlB0 >> 4;
  const int rrB1 = rlB1 & 15,     rgB1 = rlB1 >> 4;

  f32x16 acc[2][2] = {};

  for (int k0 = 0; k0 < K; k0 += 64) {
#pragma unroll
    for (int cc = 0; cc < 4; ++cc) {
      int c  = w * 4 + cc;        // 0..15
      int rg = c >> 1;
      int kh = c & 1;
      int r  = rg * 16 + srow;
      size_t gk = (size_t)k0 + kh * 32 + scol;
      gl_lds16(A + (size_t)(bm + r) * K + gk, &As[c * 512]);
      gl_lds16(W + (size_t)(bn + r) * K + gk, &Ws[c * 512]);
    }
    __syncthreads();

#pragma unroll
    for (int ks = 0; ks < 4; ++ks) {
      const int g  = ks * 2 + h2;   // 8-col group within BK=64
      const int kh = g >> 2;
      const int sl = g & 3;

      bf16x8 af[2], wf[2];
      af[0] = *reinterpret_cast<const bf16x8*>(
          &As[(rgA0 * 2 + kh) * 512 + rrA0 * 32 + (sl ^ ((rrA0 >> 1) & 3)) * 8]);
      af[1] = *reinterpret_cast<const bf16x8*>(
          &As[(rgA1 * 2 + kh) * 512 + rrA1 * 32 + (sl ^ ((rrA1 >> 1) & 3)) * 8]);
      wf[0] = *reinterpret_cast<const bf16x8*>(
          &Ws[(rgB0 * 2 + kh) * 512 + rrB0 * 32 + (sl ^ ((rrB0 >> 1) & 3)) * 8]);
      wf[1] = *reinterpret_cast<const bf16x8*>(
          &Ws[(rgB1 * 2 + kh) * 512 + rrB1 * 32 + (sl ^ ((rrB1 >> 1) & 3)) * 8]);

#pragma unroll
      for (int fi = 0; fi < 2; ++fi)
#pragma unroll
        for (int fj = 0; fj < 2; ++fj)
          acc[fi][fj] = __builtin_amdgcn_mfma_f32_32x32x16_bf16(
              af[fi], wf[fj], acc[fi][fj], 0, 0, 0);
    }
    __syncthreads();
  }

#pragma unroll
  for (int fi = 0; fi < 2; ++fi) {
#pragma unroll
    for (int fj = 0; fj < 2; ++fj) {
#pragma unroll
      for (int r = 0; r < 16; ++r) {
        int row = bm + wr + fi * 32 + (r & 3) + 8 * (r >> 2) + 4 * h2;
        int col = bn + wc + fj * 32 + l31;
        float v = acc[fi][fj][r];
        if (MODE == 1) {
          v += bias[col];
          reinterpret_cast<float*>(Cv)[(size_t)row * N + col] = v;
        } else {
          int reg = col >> 10;            // 0=q, 1=k, 2=v
          int cc  = col & 1023;
          int bb  = row >> 11;            // N_ == 2048
          int n   = row & (N_ - 1);
          int hh  = cc >> 6;
          int dd  = cc & 63;
          if (reg < 2) {
            // frag-tiled F[bh][t32][s][hi][m][8]: d = 16s+8hi+j, m = n&31
            int t32 = n >> 5, m = n & 31;
            int s = dd >> 4, hb = (dd >> 3) & 1, j = dd & 7;
            reinterpret_cast<bf16*>(Cv)[(size_t)reg * MD_ +
                (size_t)(bb * H_ + hh) * BHSZ_ +
                (size_t)t32 * 2048 + s * 512 + hb * 256 + m * 8 + j] = f2b(v);
          } else {
            // Vf[bh][t32][hf][hi][hd][8]; key = 32*t32 + 16*hf + 8*hi + j
            int t32 = n >> 5, kk = n & 31;
            int hf = kk >> 4, hb = (kk >> 3) & 1, j = kk & 7;
            reinterpret_cast<bf16*>(Cv)[2 * MD_ +
                (size_t)(bb * H_ + hh) * BHSZ_ +
                (size_t)t32 * 2048 + hf * 1024 + hb * 512 + dd * 8 + j] = f2b(v);
          }
        }
      }
    }
  }
}

// ---------------------------------------------------------------------------
// In-place RoPE on frag-tiled Q and K (round-0 VERIFIED). Each thread owns
// one 16B block = (bh, t32, s, hi, m, j=0..7) -> 4 interleaved pairs, all
// with n = 32*t32 + m, i = 8s + 4hi + p. Fully coalesced 16B r/w.
// Q half additionally folds QSC_ (= SCALE * log2e).
// ---------------------------------------------------------------------------
__global__ __launch_bounds__(256) void rope_inplace(bf16* __restrict__ qf,
                                                    bf16* __restrict__ kf)
{
  const int half = blockIdx.x >> 12;        // 0 = q, 1 = k
  const int blk  = blockIdx.x & 4095;
  bf16* base = half ? kf : qf;
  const float LN_THETA = 9.210340371976184f;

  size_t e = ((size_t)blk * 256 + threadIdx.x) * 8;
  int within = (int)(e & (BHSZ_ - 1));
  int t32 = within >> 11;
  int rem = within & 2047;
  int s  = rem >> 9;
  int hb = (rem >> 8) & 1;
  int m  = (rem >> 3) & 31;
  int n  = t32 * 32 + m;

  uint4 raw = *reinterpret_cast<const uint4*>(base + e);
  unsigned int pr[4] = {raw.x, raw.y, raw.z, raw.w};
  unsigned int outw[4];
#pragma unroll
  for (int p = 0; p < 4; ++p) {
    int i = s * 8 + hb * 4 + p;
    float inv = __expf(-((float)(2 * i) / (float)HD_) * LN_THETA);
    float ang = (float)n * inv;
    float sv, cv;
    sincosf(ang, &sv, &cv);
    float a = b2f(((bf16*)&pr[p])[0]);
    float c = b2f(((bf16*)&pr[p])[1]);
    float r0 = a * cv - c * sv;
    float r1 = c * cv + a * sv;
    if (half == 0) { r0 *= QSC_; r1 *= QSC_; }
    outw[p] = pk2(r0, r1);
  }
  uint4 o = {outw[0], outw[1], outw[2], outw[3]};
  *reinterpret_cast<uint4*>(base + e) = o;
}

// ---------------------------------------------------------------------------
// Flash attention v4 + T14 issue-early (round-10 verified, T14 neutral):
// transpose formulation (S^T = K Q^T, O^T = V^T P^T, mfma_f32_32x32x16_bf16),
// shift-free softmax, 2-way key-split + LDS combine, frag-tiled operands,
// T12 permlane P-swap (round 7).
// C/D: col=lane&31, row=(reg&3)+8*(reg>>2)+4*(lane>>5)  [m74/m101].
// ---------------------------------------------------------------------------
__global__ __launch_bounds__(128) void fattn4_kernel(
    const bf16* __restrict__ Qf, const bf16* __restrict__ Kf,
    const bf16* __restrict__ Vf, bf16* __restrict__ O)
{
  __shared__ float Ls[32 * 64];
  __shared__ float Ll[64];

  const int wv   = threadIdx.x >> 6;       // key-split half 0/1
  const int lane = threadIdx.x & 63;
  const int blk  = blockIdx.x;             // 0..4095
  const int xcd  = blk & 7;
  const int j    = blk >> 3;               // 0..511
  const int qt   = 63 - (j >> 3);          // big q-tiles dispatched first
  const int bh   = xcd * 8 + (j & 7);      // 8 bh per XCD group
  const int b    = bh >> 4;
  const int h    = bh & 15;
  const int col  = lane & 31;              // q-row / hd-row within frag
  const int hi   = lane >> 5;              // lane half

  const bf16* Qb = Qf + (size_t)bh * BHSZ_ + (size_t)qt * 2048 + hi * 256 + col * 8;
  const bf16* Kb = Kf + (size_t)bh * BHSZ_ + hi * 256 + col * 8;
  const bf16* Vb = Vf + (size_t)bh * BHSZ_ + hi * 512 + col * 8;

  bf16x8 qb[4];
#pragma unroll
  for (int s = 0; s < 4; ++s)
    qb[s] = *reinterpret_cast<const bf16x8*>(Qb + s * 512);

  f32x16 o0 = {}, o1 = {};
  float lsum = 0.f;

  // prologue K-prefetch (tile index wv always exists: 64 tiles per bh)
  bf16x8 kn[4];
  {
    const bf16* kp0 = Kb + (size_t)wv * 2048;
#pragma unroll
    for (int s = 0; s < 4; ++s)
      kn[s] = *reinterpret_cast<const bf16x8*>(kp0 + s * 512);
  }

  for (int kst = wv; kst <= qt; kst += 2) {
    // current K from prefetch registers
    bf16x8 ka[4];
#pragma unroll
    for (int s = 0; s < 4; ++s) ka[s] = kn[s];

    // issue next-tile K prefetch (hides under this tile's QK+softmax+PV)
    if (kst + 2 <= qt) {
      const bf16* kp2 = Kb + (size_t)(kst + 2) * 2048;
#pragma unroll
      for (int s = 0; s < 4; ++s)
        kn[s] = *reinterpret_cast<const bf16x8*>(kp2 + s * 512);
    }

    // issue current V loads early (hides under QK+softmax)
    const bf16* vp = Vb + (size_t)kst * 2048;
    bf16x8 v00 = *reinterpret_cast<const bf16x8*>(vp);
    bf16x8 v01 = *reinterpret_cast<const bf16x8*>(vp + 256);
    bf16x8 v10 = *reinterpret_cast<const bf16x8*>(vp + 1024);
    bf16x8 v11 = *reinterpret_cast<const bf16x8*>(vp + 1024 + 256);

    f32x16 st = {};
#pragma unroll
    for (int s = 0; s < 4; ++s)
      st = __builtin_amdgcn_mfma_f32_32x32x16_bf16(ka[s], qb[s], st, 0, 0, 0);

    float pe[16];
    if (kst == qt) {
#pragma unroll
      for (int r = 0; r < 16; ++r) {
        int koff = (r & 3) + 8 * (r >> 2) + 4 * hi;
        float e = (koff <= col) ? exp2f(st[r]) : 0.f;
        pe[r] = e; lsum += e;
      }
    } else {
#pragma unroll
      for (int r = 0; r < 16; ++r) {
        float e = exp2f(st[r]);
        pe[r] = e; lsum += e;
      }
    }

#pragma unroll
    for (int hf = 0; hf < 2; ++hf) {
      unsigned int a0 = pk2t(pe[8 * hf + 0], pe[8 * hf + 1]);
      unsigned int a1 = pk2t(pe[8 * hf + 2], pe[8 * hf + 3]);
      unsigned int b0 = pk2t(pe[8 * hf + 4], pe[8 * hf + 5]);
      unsigned int b1 = pk2t(pe[8 * hf + 6], pe[8 * hf + 7]);
      plswap(a0, b0);            // a0 -> pb.x, b0 -> pb.z
      plswap(a1, b1);            // a1 -> pb.y, b1 -> pb.w
      union { uint4 u; bf16x8 v; } pb;
      pb.u.x = a0;
      pb.u.y = a1;
      pb.u.z = b0;
      pb.u.w = b1;

      bf16x8 va = hf ? v10 : v00;
      bf16x8 vb = hf ? v11 : v01;
      o0 = __builtin_amdgcn_mfma_f32_32x32x16_bf16(va, pb.v, o0, 0, 0, 0);
      o1 = __builtin_amdgcn_mfma_f32_32x32x16_bf16(vb, pb.v, o1, 0, 0, 0);
    }
  }

  if (wv == 1) {
#pragma unroll
    for (int r = 0; r < 16; ++r) {
      Ls[r * 64 + lane]        = o0[r];
      Ls[(16 + r) * 64 + lane] = o1[r];
    }
    Ll[lane] = lsum;
  }
  __syncthreads();
  if (wv == 0) {
    float lt = lsum + Ll[lane];
    lt += __shfl_xor(lt, 32);
    float inv = 1.f / lt;
#pragma unroll
    for (int r = 0; r < 16; ++r) {
      o0[r] = (o0[r] + Ls[r * 64 + lane]) * inv;
      o1[r] = (o1[r] + Ls[(16 + r) * 64 + lane]) * inv;
    }
    bf16* Op = O + ((size_t)(b * N_ + 32 * qt + col)) * D_ + h * HD_;
#pragma unroll
    for (int g = 0; g < 4; ++g) {
      uint2 u;
      u.x = pk2(o0[4 * g + 0], o0[4 * g + 1]);
      u.y = pk2(o0[4 * g + 2], o0[4 * g + 3]);
      *reinterpret_cast<uint2*>(Op + 8 * g + 4 * hi) = u;
      u.x = pk2(o1[4 * g + 0], o1[4 * g + 1]);
      u.y = pk2(o1[4 * g + 2], o1[4 * g + 3]);
      *reinterpret_cast<uint2*>(Op + 32 + 8 * g + 4 * hi) = u;
    }
  }
}

// ---------------------------------------------------------------------------
extern "C" void kernel_launch(void* const* d_in, const int* in_sizes, int n_in,
                              void* d_out, int out_size, void* d_ws, size_t ws_size,
                              hipStream_t stream)
{
  const float* x  = (const float*)d_in[0];
  const float* Wq = (const float*)d_in[1];
  const float* Wk = (const float*)d_in[2];
  const float* Wv = (const float*)d_in[3];
  const float* Wo = (const float*)d_in[4];
  const float* bo = (const float*)d_in[5];
  float* out = (float*)d_out;

  const int M = B_ * N_;                    // 8192

  bf16* xb  = (bf16*)d_ws;                  // x bf16; dead after QKV -> ao
  bf16* qf  = xb + MD_;                     // Qf | Kf | Vf contiguous slabs
  bf16* kf  = qf + MD_;
  bf16* vf  = kf + MD_;
  bf16* Wqb = vf + MD_;                     // Wq|Wk|Wv|Wo bf16
  bf16* Wob = Wqb + 3 * DD_;
  bf16* ao  = xb;

  cvt_all<<<6144, 256, 0, stream>>>(x, Wq, Wk, Wv, Wo, xb, Wqb);

  // fused QKV: C[8192, 3072] vs [Wq;Wk;Wv]; writes Qf,Kf,Vf frag-tiled
  mgemm<0><<<dim3(24, 64), 256, 0, stream>>>(xb, Wqb, nullptr, qf, M, 3 * D_, D_);

  // in-place RoPE on Qf (with QSC fold) and Kf: 2 * 4096 blocks
  rope_inplace<<<8192, 256, 0, stream>>>(qf, kf);

  // one block (2 key-split waves) per (bh, 32-row q-tile): 4096 blocks
  fattn4_kernel<<<4096, 128, 0, stream>>>(qf, kf, vf, ao);

  mgemm<1><<<dim3(8, 64), 256, 0, stream>>>(ao, Wob, bo, out, M, D_, D_);
}